// Round 7
// baseline (45.160 us; speedup 1.0000x reference)
//
#include <hip/hip_runtime.h>

// RNNFFT: depth-10 radix-2 butterfly network over last dim (1024).
// v = x; for l = 9..0: y = B_l(w_l * v); v = (l==1) ? y : x + y
// Pairs at level l: (e, e^h), h = 512>>l. Twiddle: bw[OFF[l] + (e & (n_l-1))].
// Mix (einsum 'ij,...ik->...jk' => lw^T): role-j: y = lw[j][j]*t_self + lw[1-j][j]*t_partner.
// One wave per vector, 16 elems/lane (e = lane*16 + r):
//   levels 9..6 (h=8,4,2,1): in-register pairs (r, r^h), lane-uniform twiddles (SGPR)
//   levels 5..0: cross-lane partner exchange with lane mask 32>>l:
//     mask 1  -> DPP quad_perm [1,0,3,2]   (VALU, ~0 latency)
//     mask 2  -> DPP quad_perm [2,3,0,1]   (VALU)
//     mask 4  -> ds_swizzle 0x101F         (DS, immediate addr)
//     mask 8  -> ds_swizzle 0x201F
//     mask 16 -> ds_swizzle 0x401F
//     mask 32 -> permlane32_swap + select  (VALU)
//       v_permlane32_swap_b32 vdst,vsrc: vdst[0:31]<-vsrc[32:63], vsrc[32:63]<-vdst_old[0:31].
//       With both = t: r[0][lane] = t[lane+32] (lane<32) / t[lane] (lane>=32)
//                      r[1][lane] = t[lane]    (lane<32) / t[lane-32] (lane>=32)
//       partner(lane^32) = lane<32 ? r[0] : r[1].
// R4 post-mortem: latency-bound (VALUBusy 24% at both 32% and 54% occupancy).
// This round: waves_per_eu(4,8) to allow 8 waves/SIMD at VGPR<=64, DS ops
// 96->48/wave with 3 levels on zero-latency VALU paths, residual fused in FMA.

constexpr int VECLEN = 1024;

typedef int v2i __attribute__((ext_vector_type(2)));

template<int L>
__device__ __forceinline__ float partner(float t, int lane) {
  const int ti = __float_as_int(t);
  if constexpr (L == 5) {          // lane ^ 1
    return __int_as_float(__builtin_amdgcn_update_dpp(0, ti, 0xB1, 0xF, 0xF, true));
  } else if constexpr (L == 4) {   // lane ^ 2
    return __int_as_float(__builtin_amdgcn_update_dpp(0, ti, 0x4E, 0xF, 0xF, true));
  } else if constexpr (L == 3) {   // lane ^ 4
    return __int_as_float(__builtin_amdgcn_ds_swizzle(ti, 0x101F));
  } else if constexpr (L == 2) {   // lane ^ 8
    return __int_as_float(__builtin_amdgcn_ds_swizzle(ti, 0x201F));
  } else if constexpr (L == 1) {   // lane ^ 16
    return __int_as_float(__builtin_amdgcn_ds_swizzle(ti, 0x401F));
  } else {                         // L == 0: lane ^ 32
    v2i r = __builtin_amdgcn_permlane32_swap(ti, ti, false, false);
    return __int_as_float((lane & 32) ? r[1] : r[0]);
  }
}

template<int L, bool RESL>
__device__ __forceinline__ void level_inlane(float (&v)[16], const float (&xr)[16],
                                             const float* __restrict__ bw,
                                             const float* __restrict__ lw) {
  constexpr int n = VECLEN >> L;          // 16, 8, 4, 2
  constexpr int h = n >> 1;               // 8, 4, 2, 1
  constexpr int off = 2048 - (2048 >> L); // OFFSETS[L]
  float w[n];                              // lane-uniform -> scalar (SGPR) loads
#pragma unroll
  for (int i = 0; i < n; ++i) w[i] = bw[off + i];
  const float l00 = lw[L * 4 + 0], l01 = lw[L * 4 + 1];
  const float l10 = lw[L * 4 + 2], l11 = lw[L * 4 + 3];
#pragma unroll
  for (int r = 0; r < 16; ++r) {
    if ((r & h) == 0) {
      const int q = r ^ h;
      const float t0 = w[r & (n - 1)] * v[r];
      const float t1 = w[q & (n - 1)] * v[q];
      const float b0 = RESL ? __builtin_fmaf(l10, t1, xr[r]) : l10 * t1;
      const float b1 = RESL ? __builtin_fmaf(l01, t0, xr[q]) : l01 * t0;
      v[r] = __builtin_fmaf(l00, t0, b0);   // role 0
      v[q] = __builtin_fmaf(l11, t1, b1);   // role 1
    }
  }
}

template<int L, bool RESL>
__device__ __forceinline__ void level_cross(float (&v)[16], const float (&xr)[16],
                                            const float (&w)[16],
                                            const float* __restrict__ lw, int lane) {
  const int role = (lane >> (5 - L)) & 1;
  const float l00 = lw[L * 4 + 0], l01 = lw[L * 4 + 1];
  const float l10 = lw[L * 4 + 2], l11 = lw[L * 4 + 3];
  const float cs = role ? l11 : l00;      // coeff on own t
  const float cp = role ? l01 : l10;      // coeff on partner t
  float t[16];
#pragma unroll
  for (int r = 0; r < 16; ++r) t[r] = w[r] * v[r];   // all muls first -> exchange ILP
#pragma unroll
  for (int r = 0; r < 16; ++r) {
    const float tp = partner<L>(t[r], lane);
    const float a = RESL ? __builtin_fmaf(cp, tp, xr[r]) : cp * tp;
    v[r] = __builtin_fmaf(cs, t[r], a);
  }
}

template<int L>
__device__ __forceinline__ void loadw(float (&w)[16], const float* __restrict__ bw, int lane) {
  constexpr int n = VECLEN >> L;
  constexpr int off = 2048 - (2048 >> L);  // OFFSETS[L]
  const int wbase = off + ((lane * 16) & (n - 1));
#pragma unroll
  for (int k = 0; k < 4; ++k) {
    const float4 f = *reinterpret_cast<const float4*>(bw + wbase + 4 * k);
    w[4 * k + 0] = f.x; w[4 * k + 1] = f.y; w[4 * k + 2] = f.z; w[4 * k + 3] = f.w;
  }
}

__global__ __launch_bounds__(256)
__attribute__((amdgpu_waves_per_eu(4, 8)))
void rnnfft_kernel(const float* __restrict__ x,
                   const float* __restrict__ bw,
                   const float* __restrict__ lw,
                   float* __restrict__ out, int nvec) {
  const int wid = blockIdx.x * 4 + (threadIdx.x >> 6);   // wave id = vector id
  const int lane = threadIdx.x & 63;
  if (wid >= nvec) return;
  const size_t base = (size_t)wid * VECLEN + lane * 16;

  float v[16], xr[16];
#pragma unroll
  for (int k = 0; k < 4; ++k) {
    const float4 f = *reinterpret_cast<const float4*>(x + base + 4 * k);
    xr[4 * k + 0] = f.x; xr[4 * k + 1] = f.y;
    xr[4 * k + 2] = f.z; xr[4 * k + 3] = f.w;
  }

  // Prefetch twiddles for the first two cross levels (land during in-lane work).
  float wA[16], wB[16];
  loadw<5>(wA, bw, lane);
  loadw<4>(wB, bw, lane);

#pragma unroll
  for (int r = 0; r < 16; ++r) v[r] = xr[r];

  // Deepest level first (adjacent pairs), unwinding to level 0 (halves).
  level_inlane<9, true >(v, xr, bw, lw);
  level_inlane<8, true >(v, xr, bw, lw);
  level_inlane<7, true >(v, xr, bw, lw);
  level_inlane<6, true >(v, xr, bw, lw);

  level_cross<5, true >(v, xr, wA, lw, lane);
  loadw<3>(wA, bw, lane);
  level_cross<4, true >(v, xr, wB, lw, lane);
  loadw<2>(wB, bw, lane);
  level_cross<3, true >(v, xr, wA, lw, lane);
  loadw<1>(wA, bw, lane);
  level_cross<2, true >(v, xr, wB, lw, lane);
  loadw<0>(wB, bw, lane);
  level_cross<1, false>(v, xr, wA, lw, lane);  // RES[1] = False
  level_cross<0, true >(v, xr, wB, lw, lane);

#pragma unroll
  for (int k = 0; k < 4; ++k) {
    float4 f;
    f.x = v[4 * k + 0]; f.y = v[4 * k + 1];
    f.z = v[4 * k + 2]; f.w = v[4 * k + 3];
    *reinterpret_cast<float4*>(out + base + 4 * k) = f;
  }
}

extern "C" void kernel_launch(void* const* d_in, const int* in_sizes, int n_in,
                              void* d_out, int out_size, void* d_ws, size_t ws_size,
                              hipStream_t stream) {
  const float* x  = (const float*)d_in[0];
  const float* bw = (const float*)d_in[1];
  const float* lw = (const float*)d_in[2];
  float* out = (float*)d_out;
  const int nvec = in_sizes[0] / VECLEN;        // 16384 vectors
  const int wpb = 4;                            // waves per block (256 threads)
  const int blocks = (nvec + wpb - 1) / wpb;
  rnnfft_kernel<<<blocks, 256, 0, stream>>>(x, bw, lw, out, nvec);
}

// Round 8
// 39.891 us; speedup vs baseline: 1.1321x; 1.1321x over previous
//
#include <hip/hip_runtime.h>

// RNNFFT: depth-10 radix-2 butterfly network over last dim (1024).
// v = x; for l = 9..0: y = B_l(w_l * v); v = (l==1) ? y : x + y
// Pairs at level l: (e, e^h), h = 512>>l. Twiddle: bw[OFF[l] + (e & (n_l-1))].
// Mix (einsum 'ij,...ik->...jk' => lw^T): role-j: y = lw[j][j]*t_self + lw[1-j][j]*t_partner.
// One wave per vector, 16 elems/lane (e = lane*16 + r).
//
// R7 post-mortem: throughput invariant at ~10-11k VMEM instrs/us chip-wide across
// r1/r3/r7 (occupancy, DS-count, prefetch all no-ops) -> bound by per-CU VMEM
// front-end (each wave64 dwordx4 spans 16 cachelines). 24 twiddle gathers/wave
// (384 lines) re-fetch the same 8KB -> stage bw in LDS once per block; cross-level
// twiddles via ds_read_b128 with XOR swizzle (f ^ ((f>>5)&7)<<2) to kill the
// stride-64B bank pattern. Per-wave VMEM lines 512 -> 160.
// Numerics: r7's fma re-association gave absmax 0.094 (86% of threshold); revert
// to r1/r4 exact expression order (absmax 0.0). Exchange paths (DPP quad_perm,
// ds_swizzle imm, permlane32_swap) are exact permutations - kept.

constexpr int VECLEN = 1024;

typedef int v2i __attribute__((ext_vector_type(2)));

__device__ __forceinline__ int swz(int f) {      // LDS anti-conflict swizzle (float idx)
  return f ^ (((f >> 5) & 7) << 2);              // xor bits[4:2] <- bits[7:5]; keeps 16B groups
}

template<int L>
__device__ __forceinline__ float partner(float t, int lane) {
  const int ti = __float_as_int(t);
  if constexpr (L == 5) {          // lane ^ 1
    return __int_as_float(__builtin_amdgcn_update_dpp(0, ti, 0xB1, 0xF, 0xF, true));
  } else if constexpr (L == 4) {   // lane ^ 2
    return __int_as_float(__builtin_amdgcn_update_dpp(0, ti, 0x4E, 0xF, 0xF, true));
  } else if constexpr (L == 3) {   // lane ^ 4
    return __int_as_float(__builtin_amdgcn_ds_swizzle(ti, 0x101F));
  } else if constexpr (L == 2) {   // lane ^ 8
    return __int_as_float(__builtin_amdgcn_ds_swizzle(ti, 0x201F));
  } else if constexpr (L == 1) {   // lane ^ 16
    return __int_as_float(__builtin_amdgcn_ds_swizzle(ti, 0x401F));
  } else {                         // L == 0: lane ^ 32 via permlane32_swap
    v2i r = __builtin_amdgcn_permlane32_swap(ti, ti, false, false);
    return __int_as_float((lane & 32) ? r[1] : r[0]);
  }
}

template<int L, bool RESL>
__device__ __forceinline__ void level_inlane(float (&v)[16], const float (&xr)[16],
                                             const float* __restrict__ bw,
                                             const float* __restrict__ lw) {
  constexpr int n = VECLEN >> L;          // 16, 8, 4, 2
  constexpr int h = n >> 1;               // 8, 4, 2, 1
  constexpr int off = 2048 - (2048 >> L); // OFFSETS[L]
  float w[n];                              // lane-uniform -> scalar (SGPR) loads
#pragma unroll
  for (int i = 0; i < n; ++i) w[i] = bw[off + i];
  const float l00 = lw[L * 4 + 0], l01 = lw[L * 4 + 1];
  const float l10 = lw[L * 4 + 2], l11 = lw[L * 4 + 3];
#pragma unroll
  for (int r = 0; r < 16; ++r) {
    if ((r & h) == 0) {
      const int q = r ^ h;
      const float t0 = w[r & (n - 1)] * v[r];
      const float t1 = w[q & (n - 1)] * v[q];
      const float y0 = l00 * t0 + l10 * t1;   // role 0  (exact r1/r4 ordering)
      const float y1 = l01 * t0 + l11 * t1;   // role 1
      v[r] = RESL ? xr[r] + y0 : y0;
      v[q] = RESL ? xr[q] + y1 : y1;
    }
  }
}

template<int L, bool RESL>
__device__ __forceinline__ void level_cross(float (&v)[16], const float (&xr)[16],
                                            const float (&w)[16],
                                            const float* __restrict__ lw, int lane) {
  const int role = (lane >> (5 - L)) & 1;
  const float l00 = lw[L * 4 + 0], l01 = lw[L * 4 + 1];
  const float l10 = lw[L * 4 + 2], l11 = lw[L * 4 + 3];
  const float cs = role ? l11 : l00;      // coeff on own t
  const float cp = role ? l01 : l10;      // coeff on partner t
#pragma unroll
  for (int r = 0; r < 16; ++r) {
    const float t = w[r] * v[r];
    const float tp = partner<L>(t, lane);
    const float y = cs * t + cp * tp;     // exact r1/r4 ordering
    v[r] = RESL ? xr[r] + y : y;
  }
}

template<int L>
__device__ __forceinline__ void loadw_lds(float (&w)[16], const float* lds_bw, int lane) {
  constexpr int n = VECLEN >> L;
  constexpr int off = 2048 - (2048 >> L);  // OFFSETS[L]
  const int f0 = off + ((lane * 16) & (n - 1));
#pragma unroll
  for (int k = 0; k < 4; ++k) {
    const int g = swz(f0 + 4 * k);         // 16B-aligned group preserved
    const float4 f = *reinterpret_cast<const float4*>(lds_bw + g);
    w[4 * k + 0] = f.x; w[4 * k + 1] = f.y; w[4 * k + 2] = f.z; w[4 * k + 3] = f.w;
  }
}

__global__ __launch_bounds__(256)
void rnnfft_kernel(const float* __restrict__ x,
                   const float* __restrict__ bw,
                   const float* __restrict__ lw,
                   float* __restrict__ out, int nvec) {
  __shared__ float lds_bw[2016];           // cross levels use floats [0, 2016)
  const int t = threadIdx.x;
  const int wid = blockIdx.x * 4 + (t >> 6);   // wave id = vector id (grid exact)
  const int lane = t & 63;
  const size_t base = (size_t)wid * VECLEN + lane * 16;

  // Issue the 4 x-loads first so their latency overlaps the staging.
  float v[16], xr[16];
#pragma unroll
  for (int k = 0; k < 4; ++k) {
    const float4 f = *reinterpret_cast<const float4*>(x + base + 4 * k);
    xr[4 * k + 0] = f.x; xr[4 * k + 1] = f.y;
    xr[4 * k + 2] = f.z; xr[4 * k + 3] = f.w;
  }

  // Stage bw[0..2016) into LDS (swizzled), 8 floats per thread, once per block.
  if (t < 252) {
    const float4 a = *reinterpret_cast<const float4*>(bw + 8 * t);
    const float4 b = *reinterpret_cast<const float4*>(bw + 8 * t + 4);
    *reinterpret_cast<float4*>(lds_bw + swz(8 * t)) = a;
    *reinterpret_cast<float4*>(lds_bw + swz(8 * t + 4)) = b;
  }
  __syncthreads();

#pragma unroll
  for (int r = 0; r < 16; ++r) v[r] = xr[r];

  // Prefetch twiddles for the first two cross levels from LDS.
  float wA[16], wB[16];
  loadw_lds<5>(wA, lds_bw, lane);
  loadw_lds<4>(wB, lds_bw, lane);

  // Deepest level first (adjacent pairs), unwinding to level 0 (halves).
  level_inlane<9, true >(v, xr, bw, lw);
  level_inlane<8, true >(v, xr, bw, lw);
  level_inlane<7, true >(v, xr, bw, lw);
  level_inlane<6, true >(v, xr, bw, lw);

  level_cross<5, true >(v, xr, wA, lw, lane);
  loadw_lds<3>(wA, lds_bw, lane);
  level_cross<4, true >(v, xr, wB, lw, lane);
  loadw_lds<2>(wB, lds_bw, lane);
  level_cross<3, true >(v, xr, wA, lw, lane);
  loadw_lds<1>(wA, lds_bw, lane);
  level_cross<2, true >(v, xr, wB, lw, lane);
  loadw_lds<0>(wB, lds_bw, lane);
  level_cross<1, false>(v, xr, wA, lw, lane);  // RES[1] = False
  level_cross<0, true >(v, xr, wB, lw, lane);

#pragma unroll
  for (int k = 0; k < 4; ++k) {
    float4 f;
    f.x = v[4 * k + 0]; f.y = v[4 * k + 1];
    f.z = v[4 * k + 2]; f.w = v[4 * k + 3];
    *reinterpret_cast<float4*>(out + base + 4 * k) = f;
  }
}

extern "C" void kernel_launch(void* const* d_in, const int* in_sizes, int n_in,
                              void* d_out, int out_size, void* d_ws, size_t ws_size,
                              hipStream_t stream) {
  const float* x  = (const float*)d_in[0];
  const float* bw = (const float*)d_in[1];
  const float* lw = (const float*)d_in[2];
  float* out = (float*)d_out;
  const int nvec = in_sizes[0] / VECLEN;        // 16384 vectors
  const int wpb = 4;                            // waves per block (256 threads)
  const int blocks = (nvec + wpb - 1) / wpb;    // 4096, exact
  rnnfft_kernel<<<blocks, 256, 0, stream>>>(x, bw, lw, out, nvec);
}